// Round 1
// baseline (9509.954 us; speedup 1.0000x reference)
//
#include <hip/hip_runtime.h>
#include <math.h>

#define Q_N 4096
#define M_N 65536
#define D_N 1024
#define TOPK 8
#define SEGS 32
#define KPS (M_N / SEGS)       // 2048 keys per segment
#define BM 64
#define BN 64
#define BK 32
#define NSUB (KPS / BN)        // 32 subtiles per segment
#define QTILES (Q_N / BM)      // 64
#define CANDS (SEGS * TOPK)    // 256 candidates per query
#define NRES 32                // rescored candidates per query

__device__ __forceinline__ bool better(float v0, int i0, float v1, int i1) {
  return (v0 > v1) || (v0 == v1 && i0 < i1);
}

// ---------------- K1: key inverse norms ----------------
__global__ __launch_bounds__(256) void knorm_kernel(const float* __restrict__ keys,
                                                    float* __restrict__ rnk) {
  int row = blockIdx.x;
  float4 v = reinterpret_cast<const float4*>(keys + (size_t)row * D_N)[threadIdx.x];
  float s = v.x * v.x + v.y * v.y + v.z * v.z + v.w * v.w;
#pragma unroll
  for (int off = 32; off > 0; off >>= 1) s += __shfl_down(s, off);
  __shared__ float part[4];
  int lane = threadIdx.x & 63, wid = threadIdx.x >> 6;
  if (lane == 0) part[wid] = s;
  __syncthreads();
  if (threadIdx.x == 0) {
    float t = part[0] + part[1] + part[2] + part[3];
    rnk[row] = 1.0f / fmaxf(sqrtf(t), 1e-12f);
  }
}

// ---------------- K2: normalize queries ----------------
__global__ __launch_bounds__(256) void qnorm_kernel(const float* __restrict__ q,
                                                    float* __restrict__ qn) {
  int row = blockIdx.x;
  float4 v = reinterpret_cast<const float4*>(q + (size_t)row * D_N)[threadIdx.x];
  float s = v.x * v.x + v.y * v.y + v.z * v.z + v.w * v.w;
#pragma unroll
  for (int off = 32; off > 0; off >>= 1) s += __shfl_down(s, off);
  __shared__ float part[4];
  __shared__ float rinv_s;
  int lane = threadIdx.x & 63, wid = threadIdx.x >> 6;
  if (lane == 0) part[wid] = s;
  __syncthreads();
  if (threadIdx.x == 0) {
    float t = part[0] + part[1] + part[2] + part[3];
    rinv_s = 1.0f / fmaxf(sqrtf(t), 1e-12f);
  }
  __syncthreads();
  float r = rinv_s;
  float4 o;
  o.x = v.x * r; o.y = v.y * r; o.z = v.z * r; o.w = v.w * r;
  reinterpret_cast<float4*>(qn + (size_t)row * D_N)[threadIdx.x] = o;
}

// ---------------- K3: fp32 sims GEMM + fused per-segment top-8 ----------------
// grid = (SEGS, QTILES), block = 256. Each block: 64 queries x 2048 keys, K=1024.
__global__ __launch_bounds__(256) void sims_topk_kernel(const float* __restrict__ qn,
                                                        const float* __restrict__ keys,
                                                        const float* __restrict__ rnk,
                                                        float* __restrict__ cand_val,
                                                        int* __restrict__ cand_idx) {
  const int seg = blockIdx.x;
  const int qtile = blockIdx.y;
  const int qbase = qtile * BM;
  const int tid = threadIdx.x;
  const int tx = tid & 15;   // col group
  const int ty = tid >> 4;   // row group

  __shared__ float As[BK][BM + 4];   // [32][68] k-major, +4 pad keeps b128 aligned, spreads banks
  __shared__ float Bs[BK][BN + 4];
  __shared__ float sims[BM][BN + 1]; // [64][65]
  __shared__ float rnks[BN];

  // running top-8 per query row, owned by thread t (t < 64)
  float topv[TOPK];
  int topi[TOPK];
#pragma unroll
  for (int j = 0; j < TOPK; ++j) { topv[j] = -1e30f; topi[j] = 0x7fffffff; }

  for (int st = 0; st < NSUB; ++st) {
    const int kbase = seg * KPS + st * BN;
    __syncthreads();                       // protect rnks/sims from previous scan
    if (tid < BN) rnks[tid] = rnk[kbase + tid];

    float acc[4][4];
#pragma unroll
    for (int i = 0; i < 4; ++i)
#pragma unroll
      for (int j = 0; j < 4; ++j) acc[i][j] = 0.0f;

    for (int kt = 0; kt < D_N / BK; ++kt) {
      __syncthreads();                     // As/Bs free
      // stage: 64 rows x 32 cols each for A and B; 512 float4 per matrix / 256 threads = 2 each
#pragma unroll
      for (int i = 0; i < 2; ++i) {
        int idx4 = tid + 256 * i;          // 0..511
        int r = idx4 >> 3;                 // row 0..63
        int c4 = (idx4 & 7) << 2;          // col 0,4,..,28
        float4 a = *reinterpret_cast<const float4*>(
            &qn[(size_t)(qbase + r) * D_N + kt * BK + c4]);
        As[c4 + 0][r] = a.x; As[c4 + 1][r] = a.y; As[c4 + 2][r] = a.z; As[c4 + 3][r] = a.w;
        float4 b = *reinterpret_cast<const float4*>(
            &keys[(size_t)(kbase + r) * D_N + kt * BK + c4]);
        Bs[c4 + 0][r] = b.x; Bs[c4 + 1][r] = b.y; Bs[c4 + 2][r] = b.z; Bs[c4 + 3][r] = b.w;
      }
      __syncthreads();
#pragma unroll 4
      for (int kk = 0; kk < BK; ++kk) {
        float4 a = *reinterpret_cast<const float4*>(&As[kk][ty << 2]);
        float4 b = *reinterpret_cast<const float4*>(&Bs[kk][tx << 2]);
        float av[4] = {a.x, a.y, a.z, a.w};
        float bv[4] = {b.x, b.y, b.z, b.w};
#pragma unroll
        for (int i = 0; i < 4; ++i)
#pragma unroll
          for (int j = 0; j < 4; ++j) acc[i][j] += av[i] * bv[j];
      }
    }
    // write sims tile (raw dots; scale by rnk during scan)
#pragma unroll
    for (int i = 0; i < 4; ++i)
#pragma unroll
      for (int j = 0; j < 4; ++j) sims[(ty << 2) + i][(tx << 2) + j] = acc[i][j];
    __syncthreads();
    // scan: thread t < 64 owns query row t
    if (tid < BM) {
      for (int c = 0; c < BN; ++c) {
        float v = sims[tid][c] * rnks[c];
        int id = kbase + c;
        if (better(v, id, topv[TOPK - 1], topi[TOPK - 1])) {
          float cv = v; int cid = id;
#pragma unroll
          for (int p = 0; p < TOPK; ++p) {   // bubble insert, static indices only
            if (better(cv, cid, topv[p], topi[p])) {
              float tv = topv[p]; int ti = topi[p];
              topv[p] = cv; topi[p] = ti == 0 ? ti : ti, topi[p] = cid;  // swap
              cv = tv; cid = ti;
            }
          }
        }
      }
    }
  }
  // emit candidates
  if (tid < BM) {
    size_t base = (size_t)(qbase + tid) * CANDS + seg * TOPK;
#pragma unroll
    for (int j = 0; j < TOPK; ++j) {
      cand_val[base + j] = topv[j];
      cand_idx[base + j] = topi[j];
    }
  }
}

// ---------------- K4: merge + rescore + select + gather ----------------
// grid = Q_N, block = 256 (== CANDS)
__global__ __launch_bounds__(256) void merge_kernel(const float* __restrict__ qn,
                                                    const float* __restrict__ keys,
                                                    const float* __restrict__ values,
                                                    const float* __restrict__ rnk,
                                                    const float* __restrict__ cand_val,
                                                    const int* __restrict__ cand_idx,
                                                    float* __restrict__ out) {
  const int q = blockIdx.x;
  const int tid = threadIdx.x;
  __shared__ float sv[CANDS];
  __shared__ int si[CANDS];
  sv[tid] = cand_val[(size_t)q * CANDS + tid];
  si[tid] = cand_idx[(size_t)q * CANDS + tid];
  __syncthreads();
  // bitonic sort, best (desc by val, asc by idx) first
  for (int k = 2; k <= CANDS; k <<= 1) {
    for (int j = k >> 1; j > 0; j >>= 1) {
      int ixj = tid ^ j;
      if (ixj > tid) {
        float v0 = sv[tid], v1 = sv[ixj];
        int i0 = si[tid], i1 = si[ixj];
        bool desc = ((tid & k) == 0);
        bool dosw = desc ? better(v1, i1, v0, i0) : better(v0, i0, v1, i1);
        if (dosw) { sv[tid] = v1; si[tid] = i1; sv[ixj] = v0; si[ixj] = i0; }
      }
      __syncthreads();
    }
  }
  // exact fp32 rescore of top NRES candidates
  __shared__ float part[4];
  __shared__ float rsc[NRES];
  float4 qv = *reinterpret_cast<const float4*>(&qn[(size_t)q * D_N + tid * 4]);
  for (int c = 0; c < NRES; ++c) {
    int id = si[c];
    float4 kv = *reinterpret_cast<const float4*>(&keys[(size_t)id * D_N + tid * 4]);
    float s = qv.x * kv.x + qv.y * kv.y + qv.z * kv.z + qv.w * kv.w;
#pragma unroll
    for (int off = 32; off > 0; off >>= 1) s += __shfl_down(s, off);
    int lane = tid & 63, wid = tid >> 6;
    if (lane == 0) part[wid] = s;
    __syncthreads();
    if (tid == 0) rsc[c] = (part[0] + part[1] + part[2] + part[3]) * rnk[id];
    __syncthreads();
  }
  // top-8 of rescored (serial on thread 0; 32 elems)
  __shared__ int sel[TOPK];
  if (tid == 0) {
    unsigned used = 0;
    for (int j = 0; j < TOPK; ++j) {
      int best = -1;
      for (int c = 0; c < NRES; ++c) {
        if ((used >> c) & 1u) continue;
        if (best < 0 || better(rsc[c], si[c], rsc[best], si[best])) best = c;
      }
      used |= 1u << best;
      sel[j] = si[best];
    }
  }
  __syncthreads();
  // gather value rows: 8 rows x 1024 floats; one float4 per thread per row
#pragma unroll
  for (int j = 0; j < TOPK; ++j) {
    int row = sel[j];
    float4 v = *reinterpret_cast<const float4*>(&values[(size_t)row * D_N + tid * 4]);
    *reinterpret_cast<float4*>(&out[(size_t)q * (TOPK * D_N) + j * D_N + tid * 4]) = v;
  }
}

extern "C" void kernel_launch(void* const* d_in, const int* in_sizes, int n_in,
                              void* d_out, int out_size, void* d_ws, size_t ws_size,
                              hipStream_t stream) {
  const float* query  = (const float*)d_in[0];
  const float* keys   = (const float*)d_in[1];
  const float* values = (const float*)d_in[2];
  // d_in[3] = top_k scalar (always 8; out_size == Q_N*TOPK*D_N confirms)
  float* out = (float*)d_out;

  char* ws = (char*)d_ws;
  float* qn       = (float*)(ws);
  float* rnk      = (float*)(ws + (size_t)Q_N * D_N * 4);
  float* cand_val = (float*)(ws + (size_t)Q_N * D_N * 4 + (size_t)M_N * 4);
  int*   cand_idx = (int*)  (ws + (size_t)Q_N * D_N * 4 + (size_t)M_N * 4 +
                             (size_t)Q_N * CANDS * 4);

  hipLaunchKernelGGL(knorm_kernel, dim3(M_N), dim3(256), 0, stream, keys, rnk);
  hipLaunchKernelGGL(qnorm_kernel, dim3(Q_N), dim3(256), 0, stream, query, qn);
  hipLaunchKernelGGL(sims_topk_kernel, dim3(SEGS, QTILES), dim3(256), 0, stream,
                     qn, keys, rnk, cand_val, cand_idx);
  hipLaunchKernelGGL(merge_kernel, dim3(Q_N), dim3(256), 0, stream,
                     qn, keys, values, rnk, cand_val, cand_idx, out);
}

// Round 2
// 2018.512 us; speedup vs baseline: 4.7114x; 4.7114x over previous
//
#include <hip/hip_runtime.h>
#include <hip/hip_bf16.h>
#include <hip/hip_fp16.h>
#include <math.h>

#define Q_N 4096
#define M_N 65536
#define D_N 1024
#define TOPK 8
#define SEGS 32
#define KPS (M_N / SEGS)       // 2048 keys per segment
#define CANDS (SEGS * TOPK)    // 256 candidates per query
#define NRES 32                // rescored candidates per query

// MFMA path tile params
#define BM 128
#define BN 128
#define BK 32
#define NSUB (KPS / BN)        // 16 subtiles per segment
#define QT128 (Q_N / BM)       // 32 query tiles

typedef short s16x8 __attribute__((ext_vector_type(8)));
typedef float f32x4 __attribute__((ext_vector_type(4)));

__device__ __forceinline__ bool better(float v0, int i0, float v1, int i1) {
  return (v0 > v1) || (v0 == v1 && i0 < i1);
}

__device__ __forceinline__ unsigned short f2bf(float f) {
  union { __hip_bfloat16 h; unsigned short u; } c;
  c.h = __float2bfloat16(f);
  return c.u;
}
__device__ __forceinline__ unsigned short f2h(float f) {
  union { __half h; unsigned short u; } c;
  c.h = __float2half(f);
  return c.u;
}
__device__ __forceinline__ float h2f(unsigned short u) {
  union { __half h; unsigned short u; } c;
  c.u = u;
  return __half2float(c.h);
}

// async global->LDS, 16B per lane; lds base must be wave-uniform
__device__ __forceinline__ void gll16(void* lds, const void* g) {
  __builtin_amdgcn_global_load_lds(
      (const __attribute__((address_space(1))) unsigned int*)(uintptr_t)g,
      (__attribute__((address_space(3))) unsigned int*)(uintptr_t)lds, 16, 0, 0);
}

// ---------------- K1': key norms + scaled bf16 conversion ----------------
__global__ __launch_bounds__(256) void knorm_scale_kernel(const float* __restrict__ keys,
                                                          unsigned short* __restrict__ kb,
                                                          float* __restrict__ rnk) {
  int row = blockIdx.x;
  int tid = threadIdx.x;
  float4 v = reinterpret_cast<const float4*>(keys + (size_t)row * D_N)[tid];
  float s = v.x * v.x + v.y * v.y + v.z * v.z + v.w * v.w;
#pragma unroll
  for (int off = 32; off > 0; off >>= 1) s += __shfl_down(s, off);
  __shared__ float part[4];
  __shared__ float rs;
  int lane = tid & 63, wid = tid >> 6;
  if (lane == 0) part[wid] = s;
  __syncthreads();
  if (tid == 0) {
    float t = part[0] + part[1] + part[2] + part[3];
    rs = 1.0f / fmaxf(sqrtf(t), 1e-12f);
  }
  __syncthreads();
  float r = rs;
  ushort4 o;
  o.x = f2bf(v.x * r); o.y = f2bf(v.y * r); o.z = f2bf(v.z * r); o.w = f2bf(v.w * r);
  reinterpret_cast<ushort4*>(kb + (size_t)row * D_N)[tid] = o;
  if (tid == 0) rnk[row] = r;
}

// ---------------- K2': query norms -> fp32 (for rescore) + bf16 (for MFMA) ----
__global__ __launch_bounds__(256) void qnorm_dual_kernel(const float* __restrict__ q,
                                                         float* __restrict__ qn,
                                                         unsigned short* __restrict__ qb) {
  int row = blockIdx.x;
  int tid = threadIdx.x;
  float4 v = reinterpret_cast<const float4*>(q + (size_t)row * D_N)[tid];
  float s = v.x * v.x + v.y * v.y + v.z * v.z + v.w * v.w;
#pragma unroll
  for (int off = 32; off > 0; off >>= 1) s += __shfl_down(s, off);
  __shared__ float part[4];
  __shared__ float rs;
  int lane = tid & 63, wid = tid >> 6;
  if (lane == 0) part[wid] = s;
  __syncthreads();
  if (tid == 0) {
    float t = part[0] + part[1] + part[2] + part[3];
    rs = 1.0f / fmaxf(sqrtf(t), 1e-12f);
  }
  __syncthreads();
  float r = rs;
  float4 o;
  o.x = v.x * r; o.y = v.y * r; o.z = v.z * r; o.w = v.w * r;
  reinterpret_cast<float4*>(qn + (size_t)row * D_N)[tid] = o;
  ushort4 ob;
  ob.x = f2bf(o.x); ob.y = f2bf(o.y); ob.z = f2bf(o.z); ob.w = f2bf(o.w);
  reinterpret_cast<ushort4*>(qb + (size_t)row * D_N)[tid] = ob;
}

// ---------------- K3': bf16 MFMA sims + fused per-segment top-8 ----------------
// grid = QT128*SEGS (1D, XCD-chunk swizzled), block = 256 (4 waves, 2x2).
__global__ __launch_bounds__(256) void simsb_kernel(const unsigned short* __restrict__ qb,
                                                    const unsigned short* __restrict__ kb,
                                                    float* __restrict__ cand_val,
                                                    int* __restrict__ cand_idx) {
  __shared__ __align__(16) unsigned short As[BM * BK];  // 8 KB, [row][k] k-contig
  __shared__ __align__(16) unsigned short Bs[BN * BK];  // 8 KB
  __shared__ __align__(16) unsigned short Sh[BM][136];  // fp16 sims, stride 272B (16B-mult)

  const int tid = threadIdx.x;
  const int lane = tid & 63;
  const int wid = tid >> 6;

  // XCD-chunked swizzle: xcd = orig%8 gets contiguous chunk of 128 blocks,
  // ordered qtile-major within each segment (32 blocks of a seg co-resident).
  const int orig = blockIdx.x;
  const int lin = (orig & 7) * (QT128 * SEGS / 8) + (orig >> 3);
  const int seg = lin >> 5;
  const int qtile = lin & 31;
  const int qbase = qtile * BM;

  // staging geometry: wave wid covers tile rows [wid*32, wid*32+32), inst i adds 16
  const int srow = (wid << 5) + (lane >> 2);
  const int scol = (lane & 3) << 3;              // bf16 elem offset within row
  const unsigned short* aSrc = qb + (size_t)(qbase + srow) * D_N + scol;
  // fragment geometry
  const int wr64 = (wid >> 1) << 6;
  const int wc64 = (wid & 1) << 6;
  const int fr = lane & 15;
  const int fk = (lane >> 4) << 3;

  float topv[TOPK];
  int topi[TOPK];
#pragma unroll
  for (int j = 0; j < TOPK; ++j) { topv[j] = -1e30f; topi[j] = 0x7fffffff; }

  for (int st = 0; st < NSUB; ++st) {
    const int kbase = seg * KPS + st * BN;
    const unsigned short* bSrc = kb + (size_t)(kbase + srow) * D_N + scol;

    f32x4 acc[4][4];
#pragma unroll
    for (int m = 0; m < 4; ++m)
#pragma unroll
      for (int n = 0; n < 4; ++n) acc[m][n] = (f32x4)0.0f;

    for (int kt = 0; kt < D_N / BK; ++kt) {
      __syncthreads();  // previous frag reads done -> LDS free
      const unsigned short* aS = aSrc + kt * BK;
      const unsigned short* bS = bSrc + kt * BK;
      gll16(As + (wid << 10), aS);
      gll16(As + (wid << 10) + 512, aS + (size_t)16 * D_N);
      gll16(Bs + (wid << 10), bS);
      gll16(Bs + (wid << 10) + 512, bS + (size_t)16 * D_N);
      __syncthreads();  // vmcnt drained before barrier -> tiles resident
      s16x8 af[4], bf[4];
#pragma unroll
      for (int m = 0; m < 4; ++m)
        af[m] = *(const s16x8*)(As + ((wr64 + (m << 4) + fr) << 5) + fk);
#pragma unroll
      for (int n = 0; n < 4; ++n)
        bf[n] = *(const s16x8*)(Bs + ((wc64 + (n << 4) + fr) << 5) + fk);
#pragma unroll
      for (int m = 0; m < 4; ++m)
#pragma unroll
        for (int n = 0; n < 4; ++n)
          acc[m][n] = __builtin_amdgcn_mfma_f32_16x16x32_bf16(af[m], bf[n], acc[m][n], 0, 0, 0);
    }

    // park sims tile in fp16 LDS (C/D map: col = lane&15, row = (lane>>4)*4 + reg)
    const int crb = wr64 + ((lane >> 4) << 2);
    const int ccb = wc64 + fr;
#pragma unroll
    for (int m = 0; m < 4; ++m)
#pragma unroll
      for (int n = 0; n < 4; ++n)
#pragma unroll
        for (int j = 0; j < 4; ++j)
          Sh[crb + (m << 4) + j][ccb + (n << 4)] = f2h(acc[m][n][j]);
    __syncthreads();

    // parallel scan: thread owns row tid>>1, half tid&1 (64 cols), running top-8
    {
      const int r = tid >> 1;
      const int cb = (tid & 1) << 6;
#pragma unroll
      for (int c8 = 0; c8 < 8; ++c8) {
        s16x8 pk = *(const s16x8*)&Sh[r][cb + (c8 << 3)];
#pragma unroll
        for (int j = 0; j < 8; ++j) {
          float v = h2f((unsigned short)pk[j]);
          int id = kbase + cb + (c8 << 3) + j;
          if (better(v, id, topv[TOPK - 1], topi[TOPK - 1])) {
            float cv = v; int cid = id;
#pragma unroll
            for (int p = 0; p < TOPK; ++p) {
              if (better(cv, cid, topv[p], topi[p])) {
                float tv = topv[p]; int ti2 = topi[p];
                topv[p] = cv; topi[p] = cid;
                cv = tv; cid = ti2;
              }
            }
          }
        }
      }
    }
    // next subtile's K-loop barriers order scan-reads before Sh is rewritten
  }

  // merge the two half-row top-8 lists per row (reuse Sh as scratch)
  __syncthreads();
  float* mv = (float*)&Sh[0][0];       // 256*8 floats = 8 KB
  int* mi = (int*)(mv + 256 * TOPK);   // 8 KB
#pragma unroll
  for (int j = 0; j < TOPK; ++j) { mv[tid * TOPK + j] = topv[j]; mi[tid * TOPK + j] = topi[j]; }
  __syncthreads();
  if (tid < BM) {
    const float* va = mv + (2 * tid) * TOPK;
    const int* ia = mi + (2 * tid) * TOPK;
    const float* vb = va + TOPK;
    const int* ib = ia + TOPK;
    int pa = 0, pb = 0;
    size_t base = (size_t)(qbase + tid) * CANDS + seg * TOPK;
#pragma unroll
    for (int j = 0; j < TOPK; ++j) {
      bool ta = better(va[pa], ia[pa], vb[pb], ib[pb]);
      cand_val[base + j] = ta ? va[pa] : vb[pb];
      cand_idx[base + j] = ta ? ia[pa] : ib[pb];
      pa += ta ? 1 : 0;
      pb += ta ? 0 : 1;
    }
  }
}

// ---------------- fallback fp32 kernels (round-1, used if ws too small) ------
__global__ __launch_bounds__(256) void knorm_kernel(const float* __restrict__ keys,
                                                    float* __restrict__ rnk) {
  int row = blockIdx.x;
  float4 v = reinterpret_cast<const float4*>(keys + (size_t)row * D_N)[threadIdx.x];
  float s = v.x * v.x + v.y * v.y + v.z * v.z + v.w * v.w;
#pragma unroll
  for (int off = 32; off > 0; off >>= 1) s += __shfl_down(s, off);
  __shared__ float part[4];
  int lane = threadIdx.x & 63, wid = threadIdx.x >> 6;
  if (lane == 0) part[wid] = s;
  __syncthreads();
  if (threadIdx.x == 0) {
    float t = part[0] + part[1] + part[2] + part[3];
    rnk[row] = 1.0f / fmaxf(sqrtf(t), 1e-12f);
  }
}

__global__ __launch_bounds__(256) void qnorm_kernel(const float* __restrict__ q,
                                                    float* __restrict__ qn) {
  int row = blockIdx.x;
  float4 v = reinterpret_cast<const float4*>(q + (size_t)row * D_N)[threadIdx.x];
  float s = v.x * v.x + v.y * v.y + v.z * v.z + v.w * v.w;
#pragma unroll
  for (int off = 32; off > 0; off >>= 1) s += __shfl_down(s, off);
  __shared__ float part[4];
  __shared__ float rinv_s;
  int lane = threadIdx.x & 63, wid = threadIdx.x >> 6;
  if (lane == 0) part[wid] = s;
  __syncthreads();
  if (threadIdx.x == 0) {
    float t = part[0] + part[1] + part[2] + part[3];
    rinv_s = 1.0f / fmaxf(sqrtf(t), 1e-12f);
  }
  __syncthreads();
  float r = rinv_s;
  float4 o;
  o.x = v.x * r; o.y = v.y * r; o.z = v.z * r; o.w = v.w * r;
  reinterpret_cast<float4*>(qn + (size_t)row * D_N)[threadIdx.x] = o;
}

#define FBM 64
#define FBN 64
#define FBK 32
#define FNSUB (KPS / FBN)
__global__ __launch_bounds__(256) void sims_topk_kernel(const float* __restrict__ qn,
                                                        const float* __restrict__ keys,
                                                        const float* __restrict__ rnk,
                                                        float* __restrict__ cand_val,
                                                        int* __restrict__ cand_idx) {
  const int seg = blockIdx.x;
  const int qtile = blockIdx.y;
  const int qbase = qtile * FBM;
  const int tid = threadIdx.x;
  const int tx = tid & 15;
  const int ty = tid >> 4;

  __shared__ float As[FBK][FBM + 4];
  __shared__ float Bs[FBK][FBN + 4];
  __shared__ float sims[FBM][FBN + 1];
  __shared__ float rnks[FBN];

  float topv[TOPK];
  int topi[TOPK];
#pragma unroll
  for (int j = 0; j < TOPK; ++j) { topv[j] = -1e30f; topi[j] = 0x7fffffff; }

  for (int st = 0; st < FNSUB; ++st) {
    const int kbase = seg * KPS + st * FBN;
    __syncthreads();
    if (tid < FBN) rnks[tid] = rnk[kbase + tid];

    float acc[4][4];
#pragma unroll
    for (int i = 0; i < 4; ++i)
#pragma unroll
      for (int j = 0; j < 4; ++j) acc[i][j] = 0.0f;

    for (int kt = 0; kt < D_N / FBK; ++kt) {
      __syncthreads();
#pragma unroll
      for (int i = 0; i < 2; ++i) {
        int idx4 = tid + 256 * i;
        int r = idx4 >> 3;
        int c4 = (idx4 & 7) << 2;
        float4 a = *reinterpret_cast<const float4*>(
            &qn[(size_t)(qbase + r) * D_N + kt * FBK + c4]);
        As[c4 + 0][r] = a.x; As[c4 + 1][r] = a.y; As[c4 + 2][r] = a.z; As[c4 + 3][r] = a.w;
        float4 b = *reinterpret_cast<const float4*>(
            &keys[(size_t)(kbase + r) * D_N + kt * FBK + c4]);
        Bs[c4 + 0][r] = b.x; Bs[c4 + 1][r] = b.y; Bs[c4 + 2][r] = b.z; Bs[c4 + 3][r] = b.w;
      }
      __syncthreads();
#pragma unroll 4
      for (int kk = 0; kk < FBK; ++kk) {
        float4 a = *reinterpret_cast<const float4*>(&As[kk][ty << 2]);
        float4 b = *reinterpret_cast<const float4*>(&Bs[kk][tx << 2]);
        float av[4] = {a.x, a.y, a.z, a.w};
        float bv[4] = {b.x, b.y, b.z, b.w};
#pragma unroll
        for (int i = 0; i < 4; ++i)
#pragma unroll
          for (int j = 0; j < 4; ++j) acc[i][j] += av[i] * bv[j];
      }
    }
#pragma unroll
    for (int i = 0; i < 4; ++i)
#pragma unroll
      for (int j = 0; j < 4; ++j) sims[(ty << 2) + i][(tx << 2) + j] = acc[i][j];
    __syncthreads();
    if (tid < FBM) {
      for (int c = 0; c < FBN; ++c) {
        float v = sims[tid][c] * rnks[c];
        int id = kbase + c;
        if (better(v, id, topv[TOPK - 1], topi[TOPK - 1])) {
          float cv = v; int cid = id;
#pragma unroll
          for (int p = 0; p < TOPK; ++p) {
            if (better(cv, cid, topv[p], topi[p])) {
              float tv = topv[p]; int ti2 = topi[p];
              topv[p] = cv; topi[p] = cid;
              cv = tv; cid = ti2;
            }
          }
        }
      }
    }
  }
  if (tid < FBM) {
    size_t base = (size_t)(qbase + tid) * CANDS + seg * TOPK;
#pragma unroll
    for (int j = 0; j < TOPK; ++j) {
      cand_val[base + j] = topv[j];
      cand_idx[base + j] = topi[j];
    }
  }
}

// ---------------- K4: merge + exact fp32 rescore + select + gather -----------
__global__ __launch_bounds__(256) void merge_kernel(const float* __restrict__ qn,
                                                    const float* __restrict__ keys,
                                                    const float* __restrict__ values,
                                                    const float* __restrict__ rnk,
                                                    const float* __restrict__ cand_val,
                                                    const int* __restrict__ cand_idx,
                                                    float* __restrict__ out) {
  const int q = blockIdx.x;
  const int tid = threadIdx.x;
  __shared__ float sv[CANDS];
  __shared__ int si[CANDS];
  sv[tid] = cand_val[(size_t)q * CANDS + tid];
  si[tid] = cand_idx[(size_t)q * CANDS + tid];
  __syncthreads();
  for (int k = 2; k <= CANDS; k <<= 1) {
    for (int j = k >> 1; j > 0; j >>= 1) {
      int ixj = tid ^ j;
      if (ixj > tid) {
        float v0 = sv[tid], v1 = sv[ixj];
        int i0 = si[tid], i1 = si[ixj];
        bool desc = ((tid & k) == 0);
        bool dosw = desc ? better(v1, i1, v0, i0) : better(v0, i0, v1, i1);
        if (dosw) { sv[tid] = v1; si[tid] = i1; sv[ixj] = v0; si[ixj] = i0; }
      }
      __syncthreads();
    }
  }
  __shared__ float part[4];
  __shared__ float rsc[NRES];
  float4 qv = *reinterpret_cast<const float4*>(&qn[(size_t)q * D_N + tid * 4]);
  for (int c = 0; c < NRES; ++c) {
    int id = si[c];
    float4 kv = *reinterpret_cast<const float4*>(&keys[(size_t)id * D_N + tid * 4]);
    float s = qv.x * kv.x + qv.y * kv.y + qv.z * kv.z + qv.w * kv.w;
#pragma unroll
    for (int off = 32; off > 0; off >>= 1) s += __shfl_down(s, off);
    int lane = tid & 63, wid = tid >> 6;
    if (lane == 0) part[wid] = s;
    __syncthreads();
    if (tid == 0) rsc[c] = (part[0] + part[1] + part[2] + part[3]) * rnk[id];
    __syncthreads();
  }
  __shared__ int sel[TOPK];
  if (tid == 0) {
    unsigned used = 0;
    for (int j = 0; j < TOPK; ++j) {
      int best = -1;
      for (int c = 0; c < NRES; ++c) {
        if ((used >> c) & 1u) continue;
        if (best < 0 || better(rsc[c], si[c], rsc[best], si[best])) best = c;
      }
      used |= 1u << best;
      sel[j] = si[best];
    }
  }
  __syncthreads();
#pragma unroll
  for (int j = 0; j < TOPK; ++j) {
    int row = sel[j];
    float4 v = *reinterpret_cast<const float4*>(&values[(size_t)row * D_N + tid * 4]);
    *reinterpret_cast<float4*>(&out[(size_t)q * (TOPK * D_N) + j * D_N + tid * 4]) = v;
  }
}

extern "C" void kernel_launch(void* const* d_in, const int* in_sizes, int n_in,
                              void* d_out, int out_size, void* d_ws, size_t ws_size,
                              hipStream_t stream) {
  const float* query  = (const float*)d_in[0];
  const float* keys   = (const float*)d_in[1];
  const float* values = (const float*)d_in[2];
  float* out = (float*)d_out;
  char* ws = (char*)d_ws;

  const size_t offQn  = 0;
  const size_t offQb  = offQn + (size_t)Q_N * D_N * 4;
  const size_t offKb  = offQb + (size_t)Q_N * D_N * 2;
  const size_t offRnk = offKb + (size_t)M_N * D_N * 2;
  const size_t offCv  = offRnk + (size_t)M_N * 4;
  const size_t offCi  = offCv + (size_t)Q_N * CANDS * 4;
  const size_t need   = offCi + (size_t)Q_N * CANDS * 4;

  if (ws_size >= need) {
    float* qn = (float*)(ws + offQn);
    unsigned short* qb = (unsigned short*)(ws + offQb);
    unsigned short* kb = (unsigned short*)(ws + offKb);
    float* rnk = (float*)(ws + offRnk);
    float* cand_val = (float*)(ws + offCv);
    int* cand_idx = (int*)(ws + offCi);

    hipLaunchKernelGGL(knorm_scale_kernel, dim3(M_N), dim3(256), 0, stream, keys, kb, rnk);
    hipLaunchKernelGGL(qnorm_dual_kernel, dim3(Q_N), dim3(256), 0, stream, query, qn, qb);
    hipLaunchKernelGGL(simsb_kernel, dim3(QT128 * SEGS), dim3(256), 0, stream,
                       qb, kb, cand_val, cand_idx);
    hipLaunchKernelGGL(merge_kernel, dim3(Q_N), dim3(256), 0, stream,
                       qn, keys, values, rnk, cand_val, cand_idx, out);
  } else {
    // fallback: round-1 fp32 pipeline (needs ~24.3 MB)
    float* qn = (float*)(ws);
    float* rnk = (float*)(ws + (size_t)Q_N * D_N * 4);
    float* cand_val = (float*)(ws + (size_t)Q_N * D_N * 4 + (size_t)M_N * 4);
    int* cand_idx = (int*)(ws + (size_t)Q_N * D_N * 4 + (size_t)M_N * 4 +
                           (size_t)Q_N * CANDS * 4);
    hipLaunchKernelGGL(knorm_kernel, dim3(M_N), dim3(256), 0, stream, keys, rnk);
    hipLaunchKernelGGL(qnorm_kernel, dim3(Q_N), dim3(256), 0, stream, query, qn);
    hipLaunchKernelGGL(sims_topk_kernel, dim3(SEGS, Q_N / FBM), dim3(256), 0, stream,
                       qn, keys, rnk, cand_val, cand_idx);
    hipLaunchKernelGGL(merge_kernel, dim3(Q_N), dim3(256), 0, stream,
                       qn, keys, values, rnk, cand_val, cand_idx, out);
  }
}

// Round 3
// 1936.599 us; speedup vs baseline: 4.9106x; 1.0423x over previous
//
#include <hip/hip_runtime.h>
#include <hip/hip_bf16.h>
#include <hip/hip_fp16.h>
#include <math.h>

#define Q_N 4096
#define M_N 65536
#define D_N 1024
#define TOPK 8
#define SEGS 32
#define KPS (M_N / SEGS)       // 2048 keys per segment
#define CANDS (SEGS * TOPK)    // 256 candidates per query
#define NRES 32                // rescored candidates per query

// MFMA tile params
#define BM 128
#define BN 128
#define BK 32
#define NSUB (KPS / BN)        // 16 subtiles per segment
#define QT128 (Q_N / BM)       // 32 query tiles
#define NKT (D_N / BK)         // 32 K-steps per subtile

typedef short s16x8 __attribute__((ext_vector_type(8)));
typedef float f32x4 __attribute__((ext_vector_type(4)));

__device__ __forceinline__ bool better(float v0, int i0, float v1, int i1) {
  return (v0 > v1) || (v0 == v1 && i0 < i1);
}

__device__ __forceinline__ unsigned short f2bf(float f) {
  union { __hip_bfloat16 h; unsigned short u; } c;
  c.h = __float2bfloat16(f);
  return c.u;
}
__device__ __forceinline__ unsigned short f2h(float f) {
  union { __half h; unsigned short u; } c;
  c.h = __float2half(f);
  return c.u;
}
__device__ __forceinline__ float h2f(unsigned short u) {
  union { __half h; unsigned short u; } c;
  c.u = u;
  return __half2float(c.h);
}

// async global->LDS, 16B per lane; lds base wave-uniform, dest linear (lane*16)
__device__ __forceinline__ void gll16(void* lds, const void* g) {
  __builtin_amdgcn_global_load_lds(
      (const __attribute__((address_space(1))) unsigned int*)(uintptr_t)g,
      (__attribute__((address_space(3))) unsigned int*)(uintptr_t)lds, 16, 0, 0);
}

// ---------------- K1: key norms + normalized bf16 conversion ----------------
__global__ __launch_bounds__(256) void knorm_scale_kernel(const float* __restrict__ keys,
                                                          unsigned short* __restrict__ kb,
                                                          float* __restrict__ rnk) {
  int row = blockIdx.x;
  int tid = threadIdx.x;
  float4 v = reinterpret_cast<const float4*>(keys + (size_t)row * D_N)[tid];
  float s = v.x * v.x + v.y * v.y + v.z * v.z + v.w * v.w;
#pragma unroll
  for (int off = 32; off > 0; off >>= 1) s += __shfl_down(s, off);
  __shared__ float part[4];
  __shared__ float rs;
  int lane = tid & 63, wid = tid >> 6;
  if (lane == 0) part[wid] = s;
  __syncthreads();
  if (tid == 0) {
    float t = part[0] + part[1] + part[2] + part[3];
    rs = 1.0f / fmaxf(sqrtf(t), 1e-12f);
  }
  __syncthreads();
  float r = rs;
  ushort4 o;
  o.x = f2bf(v.x * r); o.y = f2bf(v.y * r); o.z = f2bf(v.z * r); o.w = f2bf(v.w * r);
  reinterpret_cast<ushort4*>(kb + (size_t)row * D_N)[tid] = o;
  if (tid == 0) rnk[row] = r;
}

// ---------------- K2: query norms -> fp32 (rescore) + bf16 (MFMA) ----------
__global__ __launch_bounds__(256) void qnorm_dual_kernel(const float* __restrict__ q,
                                                         float* __restrict__ qn,
                                                         unsigned short* __restrict__ qb) {
  int row = blockIdx.x;
  int tid = threadIdx.x;
  float4 v = reinterpret_cast<const float4*>(q + (size_t)row * D_N)[tid];
  float s = v.x * v.x + v.y * v.y + v.z * v.z + v.w * v.w;
#pragma unroll
  for (int off = 32; off > 0; off >>= 1) s += __shfl_down(s, off);
  __shared__ float part[4];
  __shared__ float rs;
  int lane = tid & 63, wid = tid >> 6;
  if (lane == 0) part[wid] = s;
  __syncthreads();
  if (tid == 0) {
    float t = part[0] + part[1] + part[2] + part[3];
    rs = 1.0f / fmaxf(sqrtf(t), 1e-12f);
  }
  __syncthreads();
  float r = rs;
  float4 o;
  o.x = v.x * r; o.y = v.y * r; o.z = v.z * r; o.w = v.w * r;
  reinterpret_cast<float4*>(qn + (size_t)row * D_N)[tid] = o;
  ushort4 ob;
  ob.x = f2bf(o.x); ob.y = f2bf(o.y); ob.z = f2bf(o.z); ob.w = f2bf(o.w);
  reinterpret_cast<ushort4*>(qb + (size_t)row * D_N)[tid] = ob;
}

// ---------------- K3: bf16 MFMA sims + fused per-segment top-8 --------------
// grid = QT128*SEGS (XCD-chunk swizzled), block = 256 (4 waves, 2x2).
// 2-phase double-buffered staging, 1 barrier/K-step, involutive XOR swizzle.
__global__ __launch_bounds__(256) void simsb_kernel(const unsigned short* __restrict__ qb,
                                                    const unsigned short* __restrict__ kb,
                                                    float* __restrict__ cand_val,
                                                    int* __restrict__ cand_idx) {
  // Sh (scan buffer) overlays the staging double-buffers: LDS = 34.8 KB -> 4 blocks/CU
  __shared__ __align__(16) union SmemU {
    struct {
      unsigned short A[2][BM * BK];  // 2 x 8 KB
      unsigned short B[2][BN * BK];  // 2 x 8 KB
    } ab;
    unsigned short Sh[BM][136];      // 34816 B fp16 sims tile (stride 272B = 17*16)
  } smem;

  const int tid = threadIdx.x;
  const int lane = tid & 63;
  const int wid = tid >> 6;

  // XCD-chunked swizzle: each XCD gets 4 whole segments (32 qtile blocks each)
  const int orig = blockIdx.x;
  const int lin = (orig & 7) * (QT128 * SEGS / 8) + (orig >> 3);
  const int seg = lin >> 5;
  const int qtile = lin & 31;
  const int qbase = qtile * BM;

  // staging geometry: wave wid stages tile rows [wid*32, wid*32+32)
  // physical LDS (linear): lane l -> row wid*32 + sel*16 + (l>>2), chunk l&3
  // involutive swizzle: chunk_logical = chunk_phys ^ ((row>>1)&3)
  const int srow = (wid << 5) + (lane >> 2);
  const int scol = (((lane & 3) ^ ((lane >> 3) & 3)) << 3);   // swizzled source col (elems)
  const unsigned short* aSrc = qb + (size_t)(qbase + srow) * D_N + scol;

  // fragment geometry (16x16x32 bf16): lane holds row fr, k-elems (lane>>4)*8
  const int wr64 = (wid >> 1) << 6;
  const int wc64 = (wid & 1) << 6;
  const int fr = lane & 15;
  const int chunk_phys = (lane >> 4) ^ ((fr >> 1) & 3);       // swizzled read chunk
  // per-lane loop-invariant frag byte offsets (ush units)
  int aOff[4], bOff[4];
#pragma unroll
  for (int m = 0; m < 4; ++m) {
    aOff[m] = ((wr64 + (m << 4) + fr) << 5) + (chunk_phys << 3);
    bOff[m] = ((wc64 + (m << 4) + fr) << 5) + (chunk_phys << 3);
  }

  float topv[TOPK];
  int topi[TOPK];
#pragma unroll
  for (int j = 0; j < TOPK; ++j) { topv[j] = -1e30f; topi[j] = 0x7fffffff; }

  for (int st = 0; st < NSUB; ++st) {
    const int kbase = seg * KPS + st * BN;
    const unsigned short* bSrc = kb + (size_t)(kbase + srow) * D_N + scol;

    f32x4 acc[4][4];
#pragma unroll
    for (int m = 0; m < 4; ++m)
#pragma unroll
      for (int n = 0; n < 4; ++n) acc[m][n] = (f32x4)0.0f;

    // prologue: stage kt=0 into buf0
    {
      unsigned short* Ad = smem.ab.A[0];
      unsigned short* Bd = smem.ab.B[0];
      gll16(Ad + (wid << 10), aSrc);
      gll16(Ad + (wid << 10) + 512, aSrc + (size_t)16 * D_N);
      gll16(Bd + (wid << 10), bSrc);
      gll16(Bd + (wid << 10) + 512, bSrc + (size_t)16 * D_N);
    }
    __syncthreads();   // drain prologue stage

    for (int kt = 0; kt < NKT; ++kt) {
      const unsigned short* Ab = smem.ab.A[kt & 1];
      const unsigned short* Bb = smem.ab.B[kt & 1];
      // frag reads of tile kt
      s16x8 af[4], bf[4];
#pragma unroll
      for (int m = 0; m < 4; ++m) af[m] = *(const s16x8*)(Ab + aOff[m]);
#pragma unroll
      for (int n = 0; n < 4; ++n) bf[n] = *(const s16x8*)(Bb + bOff[n]);
      // issue stage of tile kt+1 (overlaps lgkm waits + MFMA below)
      if (kt < NKT - 1) {
        const unsigned short* aS = aSrc + (kt + 1) * BK;
        const unsigned short* bS = bSrc + (kt + 1) * BK;
        unsigned short* Ad = smem.ab.A[(kt + 1) & 1];
        unsigned short* Bd = smem.ab.B[(kt + 1) & 1];
        gll16(Ad + (wid << 10), aS);
        gll16(Ad + (wid << 10) + 512, aS + (size_t)16 * D_N);
        gll16(Bd + (wid << 10), bS);
        gll16(Bd + (wid << 10) + 512, bS + (size_t)16 * D_N);
      }
#pragma unroll
      for (int m = 0; m < 4; ++m)
#pragma unroll
        for (int n = 0; n < 4; ++n)
          acc[m][n] = __builtin_amdgcn_mfma_f32_16x16x32_bf16(af[m], bf[n], acc[m][n], 0, 0, 0);
      __syncthreads();  // drains vmcnt(0): kt+1 resident; lgkm: all reads of buf done
    }

    // park sims tile in fp16 (C/D map: col = lane&15, row = (lane>>4)*4 + reg)
    const int crb = wr64 + ((lane >> 4) << 2);
    const int ccb = wc64 + fr;
#pragma unroll
    for (int m = 0; m < 4; ++m)
#pragma unroll
      for (int n = 0; n < 4; ++n)
#pragma unroll
        for (int j = 0; j < 4; ++j)
          smem.Sh[crb + (m << 4) + j][ccb + (n << 4)] = f2h(acc[m][n][j]);
    __syncthreads();

    // parallel scan: thread owns row tid>>1, half tid&1 (64 cols), running top-8
    {
      const int r = tid >> 1;
      const int cb = (tid & 1) << 6;
#pragma unroll
      for (int c8 = 0; c8 < 8; ++c8) {
        s16x8 pk = *(const s16x8*)&smem.Sh[r][cb + (c8 << 3)];
#pragma unroll
        for (int j = 0; j < 8; ++j) {
          float v = h2f((unsigned short)pk[j]);
          int id = kbase + cb + (c8 << 3) + j;
          if (better(v, id, topv[TOPK - 1], topi[TOPK - 1])) {
            float cv = v; int cid = id;
#pragma unroll
            for (int p = 0; p < TOPK; ++p) {
              if (better(cv, cid, topv[p], topi[p])) {
                float tv = topv[p]; int ti2 = topi[p];
                topv[p] = cv; topi[p] = cid;
                cv = tv; cid = ti2;
              }
            }
          }
        }
      }
    }
    __syncthreads();   // protect Sh until all scans done (next st re-stages over it)
  }

  // merge the two half-row top-8 lists per row (reuse Sh as scratch)
  float* mv = (float*)&smem.Sh[0][0];   // 256*8 floats = 8 KB
  int* mi = (int*)(mv + 256 * TOPK);    // 8 KB
#pragma unroll
  for (int j = 0; j < TOPK; ++j) { mv[tid * TOPK + j] = topv[j]; mi[tid * TOPK + j] = topi[j]; }
  __syncthreads();
  if (tid < BM) {
    const float* va = mv + (2 * tid) * TOPK;
    const int* ia = mi + (2 * tid) * TOPK;
    const float* vb = va + TOPK;
    const int* ib = ia + TOPK;
    int pa = 0, pb = 0;
    size_t base = (size_t)(qbase + tid) * CANDS + seg * TOPK;
#pragma unroll
    for (int j = 0; j < TOPK; ++j) {
      bool ta = better(va[pa], ia[pa], vb[pb], ib[pb]);
      cand_val[base + j] = ta ? va[pa] : vb[pb];
      cand_idx[base + j] = ta ? ia[pa] : ib[pb];
      pa += ta ? 1 : 0;
      pb += ta ? 0 : 1;
    }
  }
}

// ---------------- K4: merge + exact fp32 rescore + select + gather ---------
__global__ __launch_bounds__(256) void merge_kernel(const float* __restrict__ qn,
                                                    const float* __restrict__ keys,
                                                    const float* __restrict__ values,
                                                    const float* __restrict__ rnk,
                                                    const float* __restrict__ cand_val,
                                                    const int* __restrict__ cand_idx,
                                                    float* __restrict__ out) {
  const int q = blockIdx.x;
  const int tid = threadIdx.x;
  const int lane = tid & 63;
  const int w = tid >> 6;
  __shared__ float sv[CANDS];
  __shared__ int si[CANDS];
  sv[tid] = cand_val[(size_t)q * CANDS + tid];
  si[tid] = cand_idx[(size_t)q * CANDS + tid];
  __syncthreads();
  // bitonic sort, best (desc by val, asc by idx) first
  for (int k = 2; k <= CANDS; k <<= 1) {
    for (int j = k >> 1; j > 0; j >>= 1) {
      int ixj = tid ^ j;
      if (ixj > tid) {
        float v0 = sv[tid], v1 = sv[ixj];
        int i0 = si[tid], i1 = si[ixj];
        bool desc = ((tid & k) == 0);
        bool dosw = desc ? better(v1, i1, v0, i0) : better(v0, i0, v1, i1);
        if (dosw) { sv[tid] = v1; si[tid] = i1; sv[ixj] = v0; si[ixj] = i0; }
      }
      __syncthreads();
    }
  }
  // exact fp32 rescore, 4 candidates concurrently (one per wave), no inner barriers
  __shared__ float rsc[NRES];
  const float* qrow = &qn[(size_t)q * D_N + lane * 16];
  float4 qv0 = *reinterpret_cast<const float4*>(qrow + 0);
  float4 qv1 = *reinterpret_cast<const float4*>(qrow + 4);
  float4 qv2 = *reinterpret_cast<const float4*>(qrow + 8);
  float4 qv3 = *reinterpret_cast<const float4*>(qrow + 12);
  for (int c = w; c < NRES; c += 4) {
    int id = si[c];
    const float* kr = &keys[(size_t)id * D_N + lane * 16];
    float4 k0 = *reinterpret_cast<const float4*>(kr + 0);
    float4 k1 = *reinterpret_cast<const float4*>(kr + 4);
    float4 k2 = *reinterpret_cast<const float4*>(kr + 8);
    float4 k3 = *reinterpret_cast<const float4*>(kr + 12);
    float s = qv0.x * k0.x + qv0.y * k0.y + qv0.z * k0.z + qv0.w * k0.w
            + qv1.x * k1.x + qv1.y * k1.y + qv1.z * k1.z + qv1.w * k1.w
            + qv2.x * k2.x + qv2.y * k2.y + qv2.z * k2.z + qv2.w * k2.w
            + qv3.x * k3.x + qv3.y * k3.y + qv3.z * k3.z + qv3.w * k3.w;
#pragma unroll
    for (int off = 32; off > 0; off >>= 1) s += __shfl_down(s, off);
    if (lane == 0) rsc[c] = s * rnk[id];
  }
  __syncthreads();
  // top-8 of rescored (serial on thread 0; 32 elems)
  __shared__ int sel[TOPK];
  if (tid == 0) {
    unsigned used = 0;
    for (int j = 0; j < TOPK; ++j) {
      int best = -1;
      for (int c = 0; c < NRES; ++c) {
        if ((used >> c) & 1u) continue;
        if (best < 0 || better(rsc[c], si[c], rsc[best], si[best])) best = c;
      }
      used |= 1u << best;
      sel[j] = si[best];
    }
  }
  __syncthreads();
  // gather value rows: 8 rows x 1024 floats; one float4 per thread per row
#pragma unroll
  for (int j = 0; j < TOPK; ++j) {
    int row = sel[j];
    float4 v = *reinterpret_cast<const float4*>(&values[(size_t)row * D_N + tid * 4]);
    *reinterpret_cast<float4*>(&out[(size_t)q * (TOPK * D_N) + j * D_N + tid * 4]) = v;
  }
}

extern "C" void kernel_launch(void* const* d_in, const int* in_sizes, int n_in,
                              void* d_out, int out_size, void* d_ws, size_t ws_size,
                              hipStream_t stream) {
  const float* query  = (const float*)d_in[0];
  const float* keys   = (const float*)d_in[1];
  const float* values = (const float*)d_in[2];
  float* out = (float*)d_out;
  char* ws = (char*)d_ws;

  const size_t offQn  = 0;
  const size_t offQb  = offQn + (size_t)Q_N * D_N * 4;
  const size_t offKb  = offQb + (size_t)Q_N * D_N * 2;
  const size_t offRnk = offKb + (size_t)M_N * D_N * 2;
  const size_t offCv  = offRnk + (size_t)M_N * 4;
  const size_t offCi  = offCv + (size_t)Q_N * CANDS * 4;

  float* qn = (float*)(ws + offQn);
  unsigned short* qb = (unsigned short*)(ws + offQb);
  unsigned short* kb = (unsigned short*)(ws + offKb);
  float* rnk = (float*)(ws + offRnk);
  float* cand_val = (float*)(ws + offCv);
  int* cand_idx = (int*)(ws + offCi);

  hipLaunchKernelGGL(knorm_scale_kernel, dim3(M_N), dim3(256), 0, stream, keys, kb, rnk);
  hipLaunchKernelGGL(qnorm_dual_kernel, dim3(Q_N), dim3(256), 0, stream, query, qn, qb);
  hipLaunchKernelGGL(simsb_kernel, dim3(QT128 * SEGS), dim3(256), 0, stream,
                     qb, kb, cand_val, cand_idx);
  hipLaunchKernelGGL(merge_kernel, dim3(Q_N), dim3(256), 0, stream,
                     qn, keys, values, rnk, cand_val, cand_idx, out);
}

// Round 4
// 1704.785 us; speedup vs baseline: 5.5784x; 1.1360x over previous
//
#include <hip/hip_runtime.h>
#include <hip/hip_bf16.h>
#include <hip/hip_fp16.h>
#include <math.h>

#define Q_N 4096
#define M_N 65536
#define D_N 1024
#define TOPK 8
#define SEGS 32
#define KPS (M_N / SEGS)       // 2048 keys per segment
#define CANDS (SEGS * TOPK)    // 256 candidates per query
#define NRES 32                // rescored candidates per query

// MFMA tile params
#define BM 128
#define BN 128
#define BK 32
#define NSUB (KPS / BN)        // 16 subtiles per segment
#define QT128 (Q_N / BM)       // 32 query tiles
#define NKT (D_N / BK)         // 32 K-steps per subtile

typedef short s16x8 __attribute__((ext_vector_type(8)));
typedef float f32x4 __attribute__((ext_vector_type(4)));

__device__ __forceinline__ bool better(float v0, int i0, float v1, int i1) {
  return (v0 > v1) || (v0 == v1 && i0 < i1);
}

__device__ __forceinline__ unsigned short f2bf(float f) {
  union { __hip_bfloat16 h; unsigned short u; } c;
  c.h = __float2bfloat16(f);
  return c.u;
}
__device__ __forceinline__ unsigned short f2h(float f) {
  union { __half h; unsigned short u; } c;
  c.h = __float2half(f);
  return c.u;
}
__device__ __forceinline__ float h2f(unsigned short u) {
  union { __half h; unsigned short u; } c;
  c.u = u;
  return __half2float(c.h);
}

// async global->LDS, 16B per lane; lds base wave-uniform, dest linear (lane*16)
__device__ __forceinline__ void gll16(void* lds, const void* g) {
  __builtin_amdgcn_global_load_lds(
      (const __attribute__((address_space(1))) unsigned int*)(uintptr_t)g,
      (__attribute__((address_space(3))) unsigned int*)(uintptr_t)lds, 16, 0, 0);
}

// ---------------- K1: key norms + normalized bf16 conversion ----------------
__global__ __launch_bounds__(256) void knorm_scale_kernel(const float* __restrict__ keys,
                                                          unsigned short* __restrict__ kb,
                                                          float* __restrict__ rnk) {
  int row = blockIdx.x;
  int tid = threadIdx.x;
  float4 v = reinterpret_cast<const float4*>(keys + (size_t)row * D_N)[tid];
  float s = v.x * v.x + v.y * v.y + v.z * v.z + v.w * v.w;
#pragma unroll
  for (int off = 32; off > 0; off >>= 1) s += __shfl_down(s, off);
  __shared__ float part[4];
  __shared__ float rs;
  int lane = tid & 63, wid = tid >> 6;
  if (lane == 0) part[wid] = s;
  __syncthreads();
  if (tid == 0) {
    float t = part[0] + part[1] + part[2] + part[3];
    rs = 1.0f / fmaxf(sqrtf(t), 1e-12f);
  }
  __syncthreads();
  float r = rs;
  ushort4 o;
  o.x = f2bf(v.x * r); o.y = f2bf(v.y * r); o.z = f2bf(v.z * r); o.w = f2bf(v.w * r);
  reinterpret_cast<ushort4*>(kb + (size_t)row * D_N)[tid] = o;
  if (tid == 0) rnk[row] = r;
}

// ---------------- K2: query norms -> fp32 (rescore) + bf16 (MFMA) ----------
__global__ __launch_bounds__(256) void qnorm_dual_kernel(const float* __restrict__ q,
                                                         float* __restrict__ qn,
                                                         unsigned short* __restrict__ qb) {
  int row = blockIdx.x;
  int tid = threadIdx.x;
  float4 v = reinterpret_cast<const float4*>(q + (size_t)row * D_N)[tid];
  float s = v.x * v.x + v.y * v.y + v.z * v.z + v.w * v.w;
#pragma unroll
  for (int off = 32; off > 0; off >>= 1) s += __shfl_down(s, off);
  __shared__ float part[4];
  __shared__ float rs;
  int lane = tid & 63, wid = tid >> 6;
  if (lane == 0) part[wid] = s;
  __syncthreads();
  if (tid == 0) {
    float t = part[0] + part[1] + part[2] + part[3];
    rs = 1.0f / fmaxf(sqrtf(t), 1e-12f);
  }
  __syncthreads();
  float r = rs;
  float4 o;
  o.x = v.x * r; o.y = v.y * r; o.z = v.z * r; o.w = v.w * r;
  reinterpret_cast<float4*>(qn + (size_t)row * D_N)[tid] = o;
  ushort4 ob;
  ob.x = f2bf(o.x); ob.y = f2bf(o.y); ob.z = f2bf(o.z); ob.w = f2bf(o.w);
  reinterpret_cast<ushort4*>(qb + (size_t)row * D_N)[tid] = ob;
}

// ---------------- K3: bf16 MFMA sims + fused per-segment top-8 --------------
// grid = QT128*SEGS, block = 256 (4 waves, 2x2).
// Round-synchronized segment mapping: all blocks concurrently resident on an
// XCD share ONE key panel (L2-resident). Depth-2 counted-vmcnt pipeline (T4):
// loads stay in flight across raw s_barriers, never drained mid-loop.
__global__ __launch_bounds__(256) void simsb_kernel(const unsigned short* __restrict__ qb,
                                                    const unsigned short* __restrict__ kb,
                                                    float* __restrict__ cand_val,
                                                    int* __restrict__ cand_idx) {
  __shared__ __align__(16) union SmemU {
    struct {
      unsigned short A[2][BM * BK];  // 2 x 8 KB
      unsigned short B[2][BN * BK];  // 2 x 8 KB
    } ab;
    unsigned short Sh[BM][136];      // 34816 B fp16 sims tile (stride 272 B)
  } smem;

  const int tid = threadIdx.x;
  const int lane = tid & 63;
  const int wid = tid >> 6;

  // mapping: xcd = orig&7 (round-robin dispatch), round r = orig>>8 (4 slots/CU),
  // cu-slot = (orig>>3)&31. seg constant per (xcd, round) -> one 4MB panel per
  // XCD at a time; 32 qtiles cover the XCD's 32 CUs.
  const int orig = blockIdx.x;
  const int seg = (orig & 7) * 4 + (orig >> 8);
  const int qtile = (orig >> 3) & 31;
  const int qbase = qtile * BM;

  // staging geometry: wave wid stages tile rows [wid*32, wid*32+32)
  // involutive chunk swizzle applied on global source; LDS dest linear
  const int srow = (wid << 5) + (lane >> 2);
  const int scol = (((lane & 3) ^ ((lane >> 3) & 3)) << 3);
  const unsigned short* aSrc = qb + (size_t)(qbase + srow) * D_N + scol;

  // fragment geometry (16x16x32 bf16)
  const int wr64 = (wid >> 1) << 6;
  const int wc64 = (wid & 1) << 6;
  const int fr = lane & 15;
  const int chunk_phys = (lane >> 4) ^ ((fr >> 1) & 3);
  int aOff[4], bOff[4];
#pragma unroll
  for (int m = 0; m < 4; ++m) {
    aOff[m] = ((wr64 + (m << 4) + fr) << 5) + (chunk_phys << 3);
    bOff[m] = ((wc64 + (m << 4) + fr) << 5) + (chunk_phys << 3);
  }

  float topv[TOPK];
  int topi[TOPK];
#pragma unroll
  for (int j = 0; j < TOPK; ++j) { topv[j] = -1e30f; topi[j] = 0x7fffffff; }

  for (int st = 0; st < NSUB; ++st) {
    const int kbase = seg * KPS + st * BN;
    const unsigned short* bSrc = kb + (size_t)(kbase + srow) * D_N + scol;

    f32x4 acc[4][4];
#pragma unroll
    for (int m = 0; m < 4; ++m)
#pragma unroll
      for (int n = 0; n < 4; ++n) acc[m][n] = (f32x4)0.0f;

    // prologue: stage kt=0 -> buf0, kt=1 -> buf1 (8 loads in flight per wave)
#pragma unroll
    for (int p = 0; p < 2; ++p) {
      const unsigned short* aS = aSrc + p * BK;
      const unsigned short* bS = bSrc + p * BK;
      unsigned short* Ad = smem.ab.A[p];
      unsigned short* Bd = smem.ab.B[p];
      gll16(Ad + (wid << 10), aS);
      gll16(Ad + (wid << 10) + 512, aS + (size_t)16 * D_N);
      gll16(Bd + (wid << 10), bS);
      gll16(Bd + (wid << 10) + 512, bS + (size_t)16 * D_N);
    }

#pragma unroll 2
    for (int kt = 0; kt < NKT; ++kt) {
      // wait for own kt loads (leave kt+1's 4 in flight), then sync
      if (kt < NKT - 1) {
        asm volatile("s_waitcnt vmcnt(4)" ::: "memory");
      } else {
        asm volatile("s_waitcnt vmcnt(0)" ::: "memory");
      }
      __builtin_amdgcn_sched_barrier(0);
      __builtin_amdgcn_s_barrier();
      __builtin_amdgcn_sched_barrier(0);

      const unsigned short* Ab = smem.ab.A[kt & 1];
      const unsigned short* Bb = smem.ab.B[kt & 1];
      s16x8 af[4], bf[4];
#pragma unroll
      for (int m = 0; m < 4; ++m) af[m] = *(const s16x8*)(Ab + aOff[m]);
#pragma unroll
      for (int n = 0; n < 4; ++n) bf[n] = *(const s16x8*)(Bb + bOff[n]);
      asm volatile("s_waitcnt lgkmcnt(0)" ::: "memory");
      __builtin_amdgcn_sched_barrier(0);
      __builtin_amdgcn_s_barrier();   // all waves' frag reads done
      __builtin_amdgcn_sched_barrier(0);

      // overwrite the just-read buffer with kt+2 (stays in flight across barriers)
      if (kt + 2 < NKT) {
        const unsigned short* aS = aSrc + (kt + 2) * BK;
        const unsigned short* bS = bSrc + (kt + 2) * BK;
        unsigned short* Ad = smem.ab.A[kt & 1];
        unsigned short* Bd = smem.ab.B[kt & 1];
        gll16(Ad + (wid << 10), aS);
        gll16(Ad + (wid << 10) + 512, aS + (size_t)16 * D_N);
        gll16(Bd + (wid << 10), bS);
        gll16(Bd + (wid << 10) + 512, bS + (size_t)16 * D_N);
      }

#pragma unroll
      for (int m = 0; m < 4; ++m)
#pragma unroll
        for (int n = 0; n < 4; ++n)
          acc[m][n] = __builtin_amdgcn_mfma_f32_16x16x32_bf16(af[m], bf[n], acc[m][n], 0, 0, 0);
    }
    // K-loop done: vmcnt==0, last barrier ensured all frag reads complete.

    // park sims tile in fp16 (C/D map: col = lane&15, row = (lane>>4)*4 + reg)
    const int crb = wr64 + ((lane >> 4) << 2);
    const int ccb = wc64 + fr;
#pragma unroll
    for (int m = 0; m < 4; ++m)
#pragma unroll
      for (int n = 0; n < 4; ++n)
#pragma unroll
        for (int j = 0; j < 4; ++j)
          smem.Sh[crb + (m << 4) + j][ccb + (n << 4)] = f2h(acc[m][n][j]);
    __syncthreads();

    // parallel scan: thread owns row tid>>1, half tid&1 (64 cols), running top-8
    {
      const int r = tid >> 1;
      const int cb = (tid & 1) << 6;
#pragma unroll
      for (int c8 = 0; c8 < 8; ++c8) {
        s16x8 pk = *(const s16x8*)&smem.Sh[r][cb + (c8 << 3)];
#pragma unroll
        for (int j = 0; j < 8; ++j) {
          float v = h2f((unsigned short)pk[j]);
          int id = kbase + cb + (c8 << 3) + j;
          if (better(v, id, topv[TOPK - 1], topi[TOPK - 1])) {
            float cv = v; int cid = id;
#pragma unroll
            for (int p = 0; p < TOPK; ++p) {
              if (better(cv, cid, topv[p], topi[p])) {
                float tv = topv[p]; int ti2 = topi[p];
                topv[p] = cv; topi[p] = cid;
                cv = tv; cid = ti2;
              }
            }
          }
        }
      }
    }
    __syncthreads();   // all scans done before next subtile re-stages over Sh
  }

  // merge the two half-row top-8 lists per row (reuse Sh as scratch)
  float* mv = (float*)&smem.Sh[0][0];
  int* mi = (int*)(mv + 256 * TOPK);
#pragma unroll
  for (int j = 0; j < TOPK; ++j) { mv[tid * TOPK + j] = topv[j]; mi[tid * TOPK + j] = topi[j]; }
  __syncthreads();
  if (tid < BM) {
    const float* va = mv + (2 * tid) * TOPK;
    const int* ia = mi + (2 * tid) * TOPK;
    const float* vb = va + TOPK;
    const int* ib = ia + TOPK;
    int pa = 0, pb = 0;
    size_t base = (size_t)(qbase + tid) * CANDS + seg * TOPK;
#pragma unroll
    for (int j = 0; j < TOPK; ++j) {
      bool ta = better(va[pa], ia[pa], vb[pb], ib[pb]);
      cand_val[base + j] = ta ? va[pa] : vb[pb];
      cand_idx[base + j] = ta ? ia[pa] : ib[pb];
      pa += ta ? 1 : 0;
      pb += ta ? 0 : 1;
    }
  }
}

// ---------------- K4: merge + exact fp32 rescore + select + gather ---------
__global__ __launch_bounds__(256) void merge_kernel(const float* __restrict__ qn,
                                                    const float* __restrict__ keys,
                                                    const float* __restrict__ values,
                                                    const float* __restrict__ rnk,
                                                    const float* __restrict__ cand_val,
                                                    const int* __restrict__ cand_idx,
                                                    float* __restrict__ out) {
  const int q = blockIdx.x;
  const int tid = threadIdx.x;
  const int lane = tid & 63;
  const int w = tid >> 6;
  __shared__ float sv[CANDS];
  __shared__ int si[CANDS];
  sv[tid] = cand_val[(size_t)q * CANDS + tid];
  si[tid] = cand_idx[(size_t)q * CANDS + tid];
  __syncthreads();
  for (int k = 2; k <= CANDS; k <<= 1) {
    for (int j = k >> 1; j > 0; j >>= 1) {
      int ixj = tid ^ j;
      if (ixj > tid) {
        float v0 = sv[tid], v1 = sv[ixj];
        int i0 = si[tid], i1 = si[ixj];
        bool desc = ((tid & k) == 0);
        bool dosw = desc ? better(v1, i1, v0, i0) : better(v0, i0, v1, i1);
        if (dosw) { sv[tid] = v1; si[tid] = i1; sv[ixj] = v0; si[ixj] = i0; }
      }
      __syncthreads();
    }
  }
  __shared__ float rsc[NRES];
  const float* qrow = &qn[(size_t)q * D_N + lane * 16];
  float4 qv0 = *reinterpret_cast<const float4*>(qrow + 0);
  float4 qv1 = *reinterpret_cast<const float4*>(qrow + 4);
  float4 qv2 = *reinterpret_cast<const float4*>(qrow + 8);
  float4 qv3 = *reinterpret_cast<const float4*>(qrow + 12);
  for (int c = w; c < NRES; c += 4) {
    int id = si[c];
    const float* kr = &keys[(size_t)id * D_N + lane * 16];
    float4 k0 = *reinterpret_cast<const float4*>(kr + 0);
    float4 k1 = *reinterpret_cast<const float4*>(kr + 4);
    float4 k2 = *reinterpret_cast<const float4*>(kr + 8);
    float4 k3 = *reinterpret_cast<const float4*>(kr + 12);
    float s = qv0.x * k0.x + qv0.y * k0.y + qv0.z * k0.z + qv0.w * k0.w
            + qv1.x * k1.x + qv1.y * k1.y + qv1.z * k1.z + qv1.w * k1.w
            + qv2.x * k2.x + qv2.y * k2.y + qv2.z * k2.z + qv2.w * k2.w
            + qv3.x * k3.x + qv3.y * k3.y + qv3.z * k3.z + qv3.w * k3.w;
#pragma unroll
    for (int off = 32; off > 0; off >>= 1) s += __shfl_down(s, off);
    if (lane == 0) rsc[c] = s * rnk[id];
  }
  __syncthreads();
  __shared__ int sel[TOPK];
  if (tid == 0) {
    unsigned used = 0;
    for (int j = 0; j < TOPK; ++j) {
      int best = -1;
      for (int c = 0; c < NRES; ++c) {
        if ((used >> c) & 1u) continue;
        if (best < 0 || better(rsc[c], si[c], rsc[best], si[best])) best = c;
      }
      used |= 1u << best;
      sel[j] = si[best];
    }
  }
  __syncthreads();
#pragma unroll
  for (int j = 0; j < TOPK; ++j) {
    int row = sel[j];
    float4 v = *reinterpret_cast<const float4*>(&values[(size_t)row * D_N + tid * 4]);
    *reinterpret_cast<float4*>(&out[(size_t)q * (TOPK * D_N) + j * D_N + tid * 4]) = v;
  }
}

extern "C" void kernel_launch(void* const* d_in, const int* in_sizes, int n_in,
                              void* d_out, int out_size, void* d_ws, size_t ws_size,
                              hipStream_t stream) {
  const float* query  = (const float*)d_in[0];
  const float* keys   = (const float*)d_in[1];
  const float* values = (const float*)d_in[2];
  float* out = (float*)d_out;
  char* ws = (char*)d_ws;

  const size_t offQn  = 0;
  const size_t offQb  = offQn + (size_t)Q_N * D_N * 4;
  const size_t offKb  = offQb + (size_t)Q_N * D_N * 2;
  const size_t offRnk = offKb + (size_t)M_N * D_N * 2;
  const size_t offCv  = offRnk + (size_t)M_N * 4;
  const size_t offCi  = offCv + (size_t)Q_N * CANDS * 4;

  float* qn = (float*)(ws + offQn);
  unsigned short* qb = (unsigned short*)(ws + offQb);
  unsigned short* kb = (unsigned short*)(ws + offKb);
  float* rnk = (float*)(ws + offRnk);
  float* cand_val = (float*)(ws + offCv);
  int* cand_idx = (int*)(ws + offCi);

  hipLaunchKernelGGL(knorm_scale_kernel, dim3(M_N), dim3(256), 0, stream, keys, kb, rnk);
  hipLaunchKernelGGL(qnorm_dual_kernel, dim3(Q_N), dim3(256), 0, stream, query, qn, qb);
  hipLaunchKernelGGL(simsb_kernel, dim3(QT128 * SEGS), dim3(256), 0, stream,
                     qb, kb, cand_val, cand_idx);
  hipLaunchKernelGGL(merge_kernel, dim3(Q_N), dim3(256), 0, stream,
                     qn, keys, values, rnk, cand_val, cand_idx, out);
}

// Round 5
// 1314.807 us; speedup vs baseline: 7.2330x; 1.2966x over previous
//
#include <hip/hip_runtime.h>
#include <hip/hip_bf16.h>
#include <hip/hip_fp16.h>
#include <math.h>

#define Q_N 4096
#define M_N 65536
#define D_N 1024
#define TOPK 8
#define SEGS 32
#define KPS (M_N / SEGS)       // 2048 keys per segment
#define CANDS (SEGS * TOPK)    // 256 candidates per query
#define NRES 32                // rescored candidates per query

// MFMA tile params
#define BM 128
#define BN 128
#define BK 32
#define NSUB (KPS / BN)        // 16 subtiles per segment
#define QT128 (Q_N / BM)       // 32 query tiles
#define NKT (D_N / BK)         // 32 K-steps per subtile
#define NSTEP (NSUB * NKT)     // 512 pipeline steps per segment

typedef short s16x8 __attribute__((ext_vector_type(8)));
typedef float f32x4 __attribute__((ext_vector_type(4)));

__device__ __forceinline__ bool better(float v0, int i0, float v1, int i1) {
  return (v0 > v1) || (v0 == v1 && i0 < i1);
}

__device__ __forceinline__ unsigned short f2bf(float f) {
  union { __hip_bfloat16 h; unsigned short u; } c;
  c.h = __float2bfloat16(f);
  return c.u;
}

// async global->LDS, 16B per lane; lds base wave-uniform, dest linear (lane*16)
__device__ __forceinline__ void gll16(void* lds, const void* g) {
  __builtin_amdgcn_global_load_lds(
      (const __attribute__((address_space(1))) unsigned int*)(uintptr_t)g,
      (__attribute__((address_space(3))) unsigned int*)(uintptr_t)lds, 16, 0, 0);
}

// ---------------- K1: key norms + normalized bf16 conversion ----------------
__global__ __launch_bounds__(256) void knorm_scale_kernel(const float* __restrict__ keys,
                                                          unsigned short* __restrict__ kb,
                                                          float* __restrict__ rnk) {
  int row = blockIdx.x;
  int tid = threadIdx.x;
  float4 v = reinterpret_cast<const float4*>(keys + (size_t)row * D_N)[tid];
  float s = v.x * v.x + v.y * v.y + v.z * v.z + v.w * v.w;
#pragma unroll
  for (int off = 32; off > 0; off >>= 1) s += __shfl_down(s, off);
  __shared__ float part[4];
  __shared__ float rs;
  int lane = tid & 63, wid = tid >> 6;
  if (lane == 0) part[wid] = s;
  __syncthreads();
  if (tid == 0) {
    float t = part[0] + part[1] + part[2] + part[3];
    rs = 1.0f / fmaxf(sqrtf(t), 1e-12f);
  }
  __syncthreads();
  float r = rs;
  ushort4 o;
  o.x = f2bf(v.x * r); o.y = f2bf(v.y * r); o.z = f2bf(v.z * r); o.w = f2bf(v.w * r);
  reinterpret_cast<ushort4*>(kb + (size_t)row * D_N)[tid] = o;
  if (tid == 0) rnk[row] = r;
}

// ---------------- K2: query norms -> fp32 (rescore) + bf16 (MFMA) ----------
__global__ __launch_bounds__(256) void qnorm_dual_kernel(const float* __restrict__ q,
                                                         float* __restrict__ qn,
                                                         unsigned short* __restrict__ qb) {
  int row = blockIdx.x;
  int tid = threadIdx.x;
  float4 v = reinterpret_cast<const float4*>(q + (size_t)row * D_N)[tid];
  float s = v.x * v.x + v.y * v.y + v.z * v.z + v.w * v.w;
#pragma unroll
  for (int off = 32; off > 0; off >>= 1) s += __shfl_down(s, off);
  __shared__ float part[4];
  __shared__ float rs;
  int lane = tid & 63, wid = tid >> 6;
  if (lane == 0) part[wid] = s;
  __syncthreads();
  if (tid == 0) {
    float t = part[0] + part[1] + part[2] + part[3];
    rs = 1.0f / fmaxf(sqrtf(t), 1e-12f);
  }
  __syncthreads();
  float r = rs;
  float4 o;
  o.x = v.x * r; o.y = v.y * r; o.z = v.z * r; o.w = v.w * r;
  reinterpret_cast<float4*>(qn + (size_t)row * D_N)[tid] = o;
  ushort4 ob;
  ob.x = f2bf(o.x); ob.y = f2bf(o.y); ob.z = f2bf(o.z); ob.w = f2bf(o.w);
  reinterpret_cast<ushort4*>(qb + (size_t)row * D_N)[tid] = ob;
}

// ---------------- K3: bf16 MFMA sims + in-register per-segment top-8 --------
// grid = QT128*SEGS, block = 256 (4 waves). Wave = 32 queries x 128 keys.
// SWAPPED operands: mfma(keyfrag, queryfrag) -> D[key][query]; each lane holds
// 2 queries x 32 keys per subtile in registers -> top-8 maintained in-register,
// no LDS parking, no per-subtile barriers. One continuous 512-step pipeline
// (depth-2 counted-vmcnt, raw s_barriers, never drained mid-loop).
__global__ __launch_bounds__(256, 3) void simsb_kernel(const unsigned short* __restrict__ qb,
                                                       const unsigned short* __restrict__ kb,
                                                       float* __restrict__ cand_val,
                                                       int* __restrict__ cand_idx) {
  __shared__ __align__(16) union SmemU {
    struct {
      unsigned short A[2][BM * BK];  // 2 x 8 KB queries
      unsigned short B[2][BN * BK];  // 2 x 8 KB keys
    } ab;
    struct {
      float v[BM * 4 * TOPK];        // 16 KB: per-query 4 lane-group lists
      int i[BM * 4 * TOPK];          // 16 KB
    } mg;
  } smem;

  const int tid = threadIdx.x;
  const int lane = tid & 63;
  const int wid = tid >> 6;

  // round-synchronized mapping: XCD = orig&7, 4 rounds of 32 CU-slots
  const int orig = blockIdx.x;
  const int seg = (orig & 7) * 4 + (orig >> 8);
  const int qtile = (orig >> 3) & 31;
  const int qbase = qtile * BM;
  const int segBase = seg * KPS;

  // staging geometry: wave wid stages rows [wid*32, wid*32+32) of A and B
  // involutive chunk swizzle on global source; LDS dest linear
  const int srow = (wid << 5) + (lane >> 2);
  const int scol = (((lane & 3) ^ ((lane >> 3) & 3)) << 3);
  const unsigned short* aSeg = qb + (size_t)(qbase + srow) * D_N + scol;
  const unsigned short* bSeg = kb + (size_t)(segBase + srow) * D_N + scol;

  // fragment geometry: fr = row-within-16, g = k-chunk group
  const int fr = lane & 15;
  const int g = lane >> 4;
  const int chunk_phys = g ^ ((fr >> 1) & 3);
  // base byte/elem offsets; m/n handled by immediate offsets (m<<9 / n<<9 elems)
  const int bBase = (fr << 5) + (chunk_phys << 3);                  // keys tile
  const int aBase = (((wid << 5) + fr) << 5) + (chunk_phys << 3);   // query tile

  // per-lane running top-8 for 2 queries (q = qbase + wid*32 + n*16 + fr),
  // over this lane's key partition (keys m*16 + g*4 + j)
  float lv[2][TOPK];
  int li[2][TOPK];
#pragma unroll
  for (int n = 0; n < 2; ++n)
#pragma unroll
    for (int j = 0; j < TOPK; ++j) { lv[n][j] = -1e30f; li[n][j] = 0x7fffffff; }

  f32x4 acc[8][2];
#pragma unroll
  for (int m = 0; m < 8; ++m)
#pragma unroll
    for (int n = 0; n < 2; ++n) acc[m][n] = (f32x4)0.0f;

  // prologue: stage steps 0,1
#pragma unroll
  for (int p = 0; p < 2; ++p) {
    const unsigned short* aS = aSeg + ((p & 31) << 5);
    const unsigned short* bS = bSeg + ((p & 31) << 5);   // step<32 -> subtile 0
    unsigned short* Ad = smem.ab.A[p];
    unsigned short* Bd = smem.ab.B[p];
    gll16(Ad + (wid << 10), aS);
    gll16(Ad + (wid << 10) + 512, aS + (size_t)16 * D_N);
    gll16(Bd + (wid << 10), bS);
    gll16(Bd + (wid << 10) + 512, bS + (size_t)16 * D_N);
  }

#pragma unroll 1
  for (int u = 0; u < NSTEP; ++u) {
    if (u < NSTEP - 1) {
      asm volatile("s_waitcnt vmcnt(4)" ::: "memory");
    } else {
      asm volatile("s_waitcnt vmcnt(0)" ::: "memory");
    }
    __builtin_amdgcn_sched_barrier(0);
    __builtin_amdgcn_s_barrier();
    __builtin_amdgcn_sched_barrier(0);

    const unsigned short* Ab = smem.ab.A[u & 1];
    const unsigned short* Bb = smem.ab.B[u & 1];
    s16x8 af[8], bq[2];
#pragma unroll
    for (int m = 0; m < 8; ++m) af[m] = *(const s16x8*)(Bb + bBase + (m << 9));
#pragma unroll
    for (int n = 0; n < 2; ++n) bq[n] = *(const s16x8*)(Ab + aBase + (n << 9));
    asm volatile("s_waitcnt lgkmcnt(0)" ::: "memory");
    __builtin_amdgcn_sched_barrier(0);
    __builtin_amdgcn_s_barrier();   // all waves' frag reads done
    __builtin_amdgcn_sched_barrier(0);

    // restage the just-read buffer with step u+2 (stays in flight across barriers)
    if (u + 2 < NSTEP) {
      const int u2 = u + 2;
      const unsigned short* aS = aSeg + ((u2 & 31) << 5);
      const unsigned short* bS = bSeg + ((size_t)(u2 >> 5) << 17) + ((u2 & 31) << 5);
      unsigned short* Ad = smem.ab.A[u & 1];
      unsigned short* Bd = smem.ab.B[u & 1];
      gll16(Ad + (wid << 10), aS);
      gll16(Ad + (wid << 10) + 512, aS + (size_t)16 * D_N);
      gll16(Bd + (wid << 10), bS);
      gll16(Bd + (wid << 10) + 512, bS + (size_t)16 * D_N);
    }

#pragma unroll
    for (int m = 0; m < 8; ++m)
#pragma unroll
      for (int n = 0; n < 2; ++n)
        acc[m][n] = __builtin_amdgcn_mfma_f32_16x16x32_bf16(af[m], bq[n], acc[m][n], 0, 0, 0);

    // subtile boundary: fold acc into per-lane top-8, reset acc (register-only)
    if ((u & (NKT - 1)) == NKT - 1) {
      const int kb0 = segBase + ((u >> 5) << 7) + (g << 2);
#pragma unroll
      for (int n = 0; n < 2; ++n)
#pragma unroll
        for (int m = 0; m < 8; ++m)
#pragma unroll
          for (int j = 0; j < 4; ++j) {
            float v = acc[m][n][j];
            acc[m][n][j] = 0.0f;
            int id = kb0 + (m << 4) + j;
            if (better(v, id, lv[n][TOPK - 1], li[n][TOPK - 1])) {
              float cv = v; int ci = id;
#pragma unroll
              for (int p = 0; p < TOPK; ++p) {
                if (better(cv, ci, lv[n][p], li[n][p])) {
                  float tv = lv[n][p]; int ti = li[n][p];
                  lv[n][p] = cv; li[n][p] = ci;
                  cv = tv; ci = ti;
                }
              }
            }
          }
    }
  }

  __syncthreads();   // all LDS frag reads done before overlaying mg scratch

  // dump per-lane lists: query-local ql = wid*32 + n*16 + fr, group g
#pragma unroll
  for (int n = 0; n < 2; ++n) {
    const int ql = (wid << 5) + (n << 4) + fr;
#pragma unroll
    for (int j = 0; j < TOPK; ++j) {
      smem.mg.v[((ql << 2) + g) * TOPK + j] = lv[n][j];
      smem.mg.i[((ql << 2) + g) * TOPK + j] = li[n][j];
    }
  }
  __syncthreads();

  // thread per query: 4-way merge of the 4 sorted lane-group lists -> top-8
  if (tid < BM) {
    const int rb = tid << 5;   // 4 lists x 8
    int p0 = 0, p1 = 0, p2 = 0, p3 = 0;
    size_t base = (size_t)(qbase + tid) * CANDS + seg * TOPK;
#pragma unroll
    for (int j = 0; j < TOPK; ++j) {
      float v0 = smem.mg.v[rb + 0 + p0];  int i0 = smem.mg.i[rb + 0 + p0];
      float v1 = smem.mg.v[rb + 8 + p1];  int i1 = smem.mg.i[rb + 8 + p1];
      float v2 = smem.mg.v[rb + 16 + p2]; int i2 = smem.mg.i[rb + 16 + p2];
      float v3 = smem.mg.v[rb + 24 + p3]; int i3 = smem.mg.i[rb + 24 + p3];
      float bv = v0; int bi = i0; int sel = 0;
      if (better(v1, i1, bv, bi)) { bv = v1; bi = i1; sel = 1; }
      if (better(v2, i2, bv, bi)) { bv = v2; bi = i2; sel = 2; }
      if (better(v3, i3, bv, bi)) { bv = v3; bi = i3; sel = 3; }
      cand_val[base + j] = bv;
      cand_idx[base + j] = bi;
      p0 += (sel == 0); p1 += (sel == 1); p2 += (sel == 2); p3 += (sel == 3);
    }
  }
}

// ---------------- K4: merge + exact fp32 rescore + select + gather ---------
__global__ __launch_bounds__(256) void merge_kernel(const float* __restrict__ qn,
                                                    const float* __restrict__ keys,
                                                    const float* __restrict__ values,
                                                    const float* __restrict__ rnk,
                                                    const float* __restrict__ cand_val,
                                                    const int* __restrict__ cand_idx,
                                                    float* __restrict__ out) {
  const int q = blockIdx.x;
  const int tid = threadIdx.x;
  const int lane = tid & 63;
  const int w = tid >> 6;
  __shared__ float sv[CANDS];
  __shared__ int si[CANDS];
  sv[tid] = cand_val[(size_t)q * CANDS + tid];
  si[tid] = cand_idx[(size_t)q * CANDS + tid];
  __syncthreads();
  for (int k = 2; k <= CANDS; k <<= 1) {
    for (int j = k >> 1; j > 0; j >>= 1) {
      int ixj = tid ^ j;
      if (ixj > tid) {
        float v0 = sv[tid], v1 = sv[ixj];
        int i0 = si[tid], i1 = si[ixj];
        bool desc = ((tid & k) == 0);
        bool dosw = desc ? better(v1, i1, v0, i0) : better(v0, i0, v1, i1);
        if (dosw) { sv[tid] = v1; si[tid] = i1; sv[ixj] = v0; si[ixj] = i0; }
      }
      __syncthreads();
    }
  }
  __shared__ float rsc[NRES];
  const float* qrow = &qn[(size_t)q * D_N + lane * 16];
  float4 qv0 = *reinterpret_cast<const float4*>(qrow + 0);
  float4 qv1 = *reinterpret_cast<const float4*>(qrow + 4);
  float4 qv2 = *reinterpret_cast<const float4*>(qrow + 8);
  float4 qv3 = *reinterpret_cast<const float4*>(qrow + 12);
  for (int c = w; c < NRES; c += 4) {
    int id = si[c];
    const float* kr = &keys[(size_t)id * D_N + lane * 16];
    float4 k0 = *reinterpret_cast<const float4*>(kr + 0);
    float4 k1 = *reinterpret_cast<const float4*>(kr + 4);
    float4 k2 = *reinterpret_cast<const float4*>(kr + 8);
    float4 k3 = *reinterpret_cast<const float4*>(kr + 12);
    float s = qv0.x * k0.x + qv0.y * k0.y + qv0.z * k0.z + qv0.w * k0.w
            + qv1.x * k1.x + qv1.y * k1.y + qv1.z * k1.z + qv1.w * k1.w
            + qv2.x * k2.x + qv2.y * k2.y + qv2.z * k2.z + qv2.w * k2.w
            + qv3.x * k3.x + qv3.y * k3.y + qv3.z * k3.z + qv3.w * k3.w;
#pragma unroll
    for (int off = 32; off > 0; off >>= 1) s += __shfl_down(s, off);
    if (lane == 0) rsc[c] = s * rnk[id];
  }
  __syncthreads();
  __shared__ int sel[TOPK];
  if (tid == 0) {
    unsigned used = 0;
    for (int j = 0; j < TOPK; ++j) {
      int best = -1;
      for (int c = 0; c < NRES; ++c) {
        if ((used >> c) & 1u) continue;
        if (best < 0 || better(rsc[c], si[c], rsc[best], si[best])) best = c;
      }
      used |= 1u << best;
      sel[j] = si[best];
    }
  }
  __syncthreads();
#pragma unroll
  for (int j = 0; j < TOPK; ++j) {
    int row = sel[j];
    float4 v = *reinterpret_cast<const float4*>(&values[(size_t)row * D_N + tid * 4]);
    *reinterpret_cast<float4*>(&out[(size_t)q * (TOPK * D_N) + j * D_N + tid * 4]) = v;
  }
}

extern "C" void kernel_launch(void* const* d_in, const int* in_sizes, int n_in,
                              void* d_out, int out_size, void* d_ws, size_t ws_size,
                              hipStream_t stream) {
  const float* query  = (const float*)d_in[0];
  const float* keys   = (const float*)d_in[1];
  const float* values = (const float*)d_in[2];
  float* out = (float*)d_out;
  char* ws = (char*)d_ws;

  const size_t offQn  = 0;
  const size_t offQb  = offQn + (size_t)Q_N * D_N * 4;
  const size_t offKb  = offQb + (size_t)Q_N * D_N * 2;
  const size_t offRnk = offKb + (size_t)M_N * D_N * 2;
  const size_t offCv  = offRnk + (size_t)M_N * 4;
  const size_t offCi  = offCv + (size_t)Q_N * CANDS * 4;

  float* qn = (float*)(ws + offQn);
  unsigned short* qb = (unsigned short*)(ws + offQb);
  unsigned short* kb = (unsigned short*)(ws + offKb);
  float* rnk = (float*)(ws + offRnk);
  float* cand_val = (float*)(ws + offCv);
  int* cand_idx = (int*)(ws + offCi);

  hipLaunchKernelGGL(knorm_scale_kernel, dim3(M_N), dim3(256), 0, stream, keys, kb, rnk);
  hipLaunchKernelGGL(qnorm_dual_kernel, dim3(Q_N), dim3(256), 0, stream, query, qn, qb);
  hipLaunchKernelGGL(simsb_kernel, dim3(QT128 * SEGS), dim3(256), 0, stream,
                     qb, kb, cand_val, cand_idx);
  hipLaunchKernelGGL(merge_kernel, dim3(Q_N), dim3(256), 0, stream,
                     qn, keys, values, rnk, cand_val, cand_idx, out);
}